// Round 8
// baseline (183.302 us; speedup 1.0000x reference)
//
#include <hip/hip_runtime.h>
#include <hip/hip_bf16.h>
#include <stdint.h>

// out = (QK^T/sqrt(d))V = Q (K^T V)/sqrt(d)   (no softmax in ref)
// F = Wq^T Wk;  G = x^T x (symmetric);  H = F G;
// Pt = [Wv H^T + bv a1^T + w a2^T + L bv a2^T]/sqrt(d)
// r[z,o] = [Wv·g + cs bv + bb (w + L bv)]/sqrt(d);  out = xb Pt^T + 1 r^T
// Round-8: 64x64 tiles (32 KiB LDS, 4-5 blocks/CU) — D=768 GEMMs were
// latency-bound at 1-3 blocks/CU with 128^2 tiles (m102 shape-curve regime).

typedef __attribute__((ext_vector_type(8))) short short8;
typedef __attribute__((ext_vector_type(8))) unsigned short ushort8;
typedef __attribute__((ext_vector_type(4))) float f32x4;
typedef __attribute__((address_space(3))) void lds_void;
typedef const __attribute__((address_space(1))) void gmem_void;

__device__ __forceinline__ unsigned short f2bf(float f) {
  union { float f; unsigned u; } v; v.f = f;
  unsigned r = v.u + 0x7fff + ((v.u >> 16) & 1);   // RNE
  return (unsigned short)(r >> 16);
}
__device__ __forceinline__ float bf2f(unsigned short u) {
  union { unsigned u; float f; } v; v.u = ((unsigned)u) << 16; return v.f;
}
__device__ __forceinline__ float wave_red(float a) {
#pragma unroll
  for (int off = 32; off; off >>= 1) a += __shfl_down(a, off);
  return a;
}

// ---------------- preamble: x->xt,xb,col-partials; Wq^T,Wk^T,Wv casts -------
__global__ __launch_bounds__(256) void preamble(
    const float* __restrict__ x, const float* __restrict__ Wq,
    const float* __restrict__ Wk, const float* __restrict__ Wv,
    unsigned short* __restrict__ xb, unsigned short* __restrict__ xt,
    unsigned short* __restrict__ wqtb, unsigned short* __restrict__ wktb,
    unsigned short* __restrict__ wvb, float* __restrict__ partials)
{
  const int bid = blockIdx.x;
  const int tid = threadIdx.x;
  if (bid < 6144) {                       // x role: 64l x 32d tile
    __shared__ float tile[64][33];
    __shared__ float pt[8][32];
    const int z = bid / 768, rem = bid % 768;
    const int l0 = (rem / 24) * 64, d0 = (rem % 24) * 32;
    const int tx = tid & 31, ty = tid >> 5;
    const float* xz = x + ((long)z * 2048 + l0) * 768 + d0;
    unsigned short* xbz = xb + ((long)z * 2048 + l0) * 768 + d0;
    float colacc = 0.f;
#pragma unroll
    for (int i = 0; i < 8; ++i) {
      float v = xz[(long)(i * 8 + ty) * 768 + tx];
      tile[i * 8 + ty][tx] = v;
      xbz[(long)(i * 8 + ty) * 768 + tx] = f2bf(v);
      colacc += v;
    }
    pt[ty][tx] = colacc;
    __syncthreads();
    unsigned short* xtz = xt + ((long)z * 768 + d0) * 2048 + l0;
#pragma unroll
    for (int i = 0; i < 4; ++i) {
      int d = i * 8 + ty;
      ushort2 o; o.x = f2bf(tile[2 * tx][d]); o.y = f2bf(tile[2 * tx + 1][d]);
      *(ushort2*)(xtz + (long)d * 2048 + 2 * tx) = o;
    }
    if (ty == 0) {
      float s = 0.f;
#pragma unroll
      for (int t = 0; t < 8; ++t) s += pt[t][tx];
      partials[((long)z * 768 + d0 + tx) * 32 + (l0 >> 6)] = s;
    }
  } else if (bid < 7296) {                // weight transpose (wq, wk)
    __shared__ float tl[32][33];
    int t = bid - 6144;
    const float* W = (t < 576) ? Wq : Wk;
    unsigned short* O = (t < 576) ? wqtb : wktb;
    t = (t >= 576) ? t - 576 : t;
    const int r0 = (t / 24) * 32, c0 = (t % 24) * 32;
    const int tx = tid & 31, ty = tid >> 5;
    for (int i = ty; i < 32; i += 8) tl[i][tx] = W[(long)(r0 + i) * 768 + c0 + tx];
    __syncthreads();
    for (int i = ty; i < 32; i += 8) O[(long)(c0 + i) * 768 + r0 + tx] = f2bf(tl[tx][i]);
  } else {                                // wv cast, 288 blocks x 2048 elems
    const int t = bid - 7296;
    const long i = ((long)t * 256 + tid) * 8;
    float4 v0 = *(const float4*)(Wv + i);
    float4 v1 = *(const float4*)(Wv + i + 4);
    unsigned short o[8];
    o[0] = f2bf(v0.x); o[1] = f2bf(v0.y); o[2] = f2bf(v0.z); o[3] = f2bf(v0.w);
    o[4] = f2bf(v1.x); o[5] = f2bf(v1.y); o[6] = f2bf(v1.z); o[7] = f2bf(v1.w);
    *(ushort8*)(wvb + i) = *(ushort8*)o;
  }
}

// ------- 64x64-tile GEMM core: BK=64, 2-phase dbuf, XOR swizzle, 32 KiB -----
// C[m,n] = scale*sum_k A[m,k]*B[n,k] (+bias).  4 waves, 32x32 quadrant each.
template<int BIAS_MODE, int OUT_BF16, int SYM>
__device__ __forceinline__ void gemm64_core(
    int z, long bm, long bn,
    unsigned short* __restrict__ As, unsigned short* __restrict__ Bs, // [2][64*64]
    const unsigned short* __restrict__ A, const unsigned short* __restrict__ B,
    const float* __restrict__ bias, const float* __restrict__ b2,
    const float* __restrict__ b3, const float* __restrict__ b4,
    void* __restrict__ Cv,
    int K, int lda, int ldb, int ldc,
    long a_bs, long b_bs, long c_bs, long bias_bs, float scale)
{
  const int tid  = threadIdx.x;
  const int wid  = tid >> 6;
  const int lane = tid & 63;
  const unsigned short* Ab = A + (long)z * a_bs;
  const unsigned short* Bb = B + (long)z * b_bs;

  f32x4 acc[2][2];
#pragma unroll
  for (int r = 0; r < 2; ++r)
#pragma unroll
    for (int c = 0; c < 2; ++c) acc[r][c] = (f32x4){0.f, 0.f, 0.f, 0.f};

  const int srow = lane >> 3;                    // 0..7
  const int scol = ((lane & 7) ^ srow) * 8;      // pre-swizzled source chunk
  const int fr   = lane & 15;
  const int xr   = lane & 7;
  const int kq   = lane >> 4;                    // 0..3

#define STAGE64(p, k0) do { \
  _Pragma("unroll") \
  for (int j_ = 0; j_ < 2; ++j_) { \
    const int r_ = wid * 16 + j_ * 8; \
    const unsigned short* ga_ = Ab + (bm + r_ + srow) * (long)lda + (k0) + scol; \
    __builtin_amdgcn_global_load_lds((gmem_void*)ga_, (lds_void*)(As + (p) * 4096 + r_ * 64), 16, 0, 0); \
    const unsigned short* gb_ = Bb + (bn + r_ + srow) * (long)ldb + (k0) + scol; \
    __builtin_amdgcn_global_load_lds((gmem_void*)gb_, (lds_void*)(Bs + (p) * 4096 + r_ * 64), 16, 0, 0); \
  } } while (0)

  const int nt = K / 64;
  STAGE64(0, 0);
  __syncthreads();

  for (int t = 0; t < nt; ++t) {
    const int p = t & 1;
    if (t + 1 < nt) STAGE64(p ^ 1, (t + 1) * 64);
    __builtin_amdgcn_s_setprio(1);
#pragma unroll
    for (int kk = 0; kk < 2; ++kk) {
      short8 af[2], bfr[2];
#pragma unroll
      for (int r = 0; r < 2; ++r) {
        const int row = (wid >> 1) * 32 + r * 16 + fr;
        af[r] = *(const short8*)(As + p * 4096 + row * 64 + (((kk * 4 + kq) ^ xr) << 3));
      }
#pragma unroll
      for (int c = 0; c < 2; ++c) {
        const int row = (wid & 1) * 32 + c * 16 + fr;
        bfr[c] = *(const short8*)(Bs + p * 4096 + row * 64 + (((kk * 4 + kq) ^ xr) << 3));
      }
#pragma unroll
      for (int r = 0; r < 2; ++r)
#pragma unroll
        for (int c = 0; c < 2; ++c)
          acc[r][c] = __builtin_amdgcn_mfma_f32_16x16x32_bf16(af[r], bfr[c], acc[r][c], 0, 0, 0);
    }
    __builtin_amdgcn_s_setprio(0);
    if (t + 1 < nt) __syncthreads();
  }
#undef STAGE64

  const int wr  = (wid >> 1) * 32;
  const int wc  = (wid & 1) * 32;
  const int cr0 = (lane >> 4) * 4;
  const int cc  = lane & 15;
#pragma unroll
  for (int r = 0; r < 2; ++r)
#pragma unroll
    for (int c = 0; c < 2; ++c)
#pragma unroll
      for (int j = 0; j < 4; ++j) {
        long row = bm + wr + r * 16 + cr0 + j;
        long col = bn + wc + c * 16 + cc;
        float v = acc[r][c][j] * scale;
        if (BIAS_MODE == 1) v += bias[z * bias_bs + col];
        else if (BIAS_MODE == 3)
          v += scale * (bias[row] * (b2[z * 768 + col] + 2048.0f * b4[col])
                        + b3[z * 768 + row] * b4[col]);
        long off = (long)z * c_bs + row * (long)ldc + col;
        if (OUT_BF16) {
          ((unsigned short*)Cv)[off] = f2bf(v);
          if (SYM && bm != bn)
            ((unsigned short*)Cv)[(long)z * c_bs + col * (long)ldc + row] = f2bf(v);
        } else {
          ((float*)Cv)[off] = v;
        }
      }
}

// ---- launch 2: G upper-tri 64^2 (0..623) + F (624..767) + c1,a2 (768..791) + s (792..799)
__global__ __launch_bounds__(256, 4) void gf_k(
    const unsigned short* xt, unsigned short* G,
    const unsigned short* wqtb, const unsigned short* wktb, unsigned short* F,
    const float* bq, const float* bk, const float* partials,
    float* c1v, float* a2v, float* sv)
{
  __shared__ unsigned short lds[2 * 2 * 64 * 64];   // 32 KiB
  unsigned short* As = lds;
  unsigned short* Bs = lds + 8192;
  const int bid = blockIdx.x, tid = threadIdx.x;
  if (bid < 624) {                        // G: 78 upper-tri 64-tiles x 8 batches
    const int z = bid & 7;
    int t = bid >> 3;
    int by = 0, off = 0, w = 12;
    while (t >= off + w) { off += w; --w; ++by; }
    const int bx = by + (t - off);
    gemm64_core<0, 1, 1>(z, (long)by * 64, (long)bx * 64, As, Bs,
        xt, xt, nullptr, nullptr, nullptr, nullptr, G,
        2048, 2048, 2048, 768, 768L * 2048, 768L * 2048, 768L * 768, 0, 1.0f);
  } else if (bid < 768) {                 // F = wqt · wkt^T (144 tiles)
    const int t = bid - 624;
    gemm64_core<0, 1, 0>(0, (long)(t / 12) * 64, (long)(t % 12) * 64, As, Bs,
        wqtb, wktb, nullptr, nullptr, nullptr, nullptr, F,
        768, 768, 768, 768, 0, 0, 0, 0, 1.0f);
  } else if (bid < 792) {                 // c1[r]=wkt[r,:]·bq ; a2[r]=wqt[r,:]·bk
    const int wid = tid >> 6, lane = tid & 63;
    const int r0 = (bid - 768) * 32;
#pragma unroll
    for (int mi = 0; mi < 8; ++mi) {
      const int r = r0 + wid * 8 + mi;
      float ac = 0.f, aa = 0.f;
      for (int k = lane; k < 768; k += 64) {
        ac += bf2f(wktb[(long)r * 768 + k]) * bq[k];
        aa += bf2f(wqtb[(long)r * 768 + k]) * bk[k];
      }
      ac = wave_red(ac); aa = wave_red(aa);
      if (lane == 0) { c1v[r] = ac; a2v[r] = aa; }
    }
  } else {                                // s[z,d] from partials
    const int z = bid - 792;
    for (int d = tid; d < 768; d += 256) {
      const float* pp = partials + ((long)z * 768 + d) * 32;
      float s = 0.f;
#pragma unroll
      for (int j = 0; j < 32; ++j) s += pp[j];
      sv[z * 768 + d] = s;
    }
  }
}

// ---- launch 3: H = F·G 64^2 (0..1151) + a1/w/g GEMVs (1152..1727) ----------
__global__ __launch_bounds__(256, 4) void hv_k(
    const unsigned short* Fb, const unsigned short* G, unsigned short* H,
    const float* Wv, const float* sv, const float* c1v,
    float* a1v, float* wvv, float* gv)
{
  __shared__ unsigned short lds[2 * 2 * 64 * 64];
  unsigned short* As = lds;
  unsigned short* Bs = lds + 8192;
  const int bid = blockIdx.x, tid = threadIdx.x;
  if (bid < 1152) {
    const int z = bid & 7, t = bid >> 3;   // t 0..143
    gemm64_core<0, 1, 0>(z, (long)(t / 12) * 64, (long)(t % 12) * 64, As, Bs,
        Fb, G, nullptr, nullptr, nullptr, nullptr, H,
        768, 768, 768, 768, 0, 768L * 768, 768L * 768, 0, 1.0f);
  } else {
    const int t = bid - 1152;             // 0..575
    const int type = t / 192, u = t % 192;
    const int z = u / 24, r0 = (u % 24) * 32;
    const int wid = tid >> 6, lane = tid & 63;
#pragma unroll
    for (int mi = 0; mi < 8; ++mi) {
      const int r = r0 + wid * 8 + mi;
      float a = 0.f;
      if (type == 0) {                    // a1[z,r] = F[r,:]·s[z,:]
        for (int k = lane; k < 768; k += 64)
          a += bf2f(Fb[(long)r * 768 + k]) * sv[z * 768 + k];
      } else if (type == 1) {             // w[z,r] = Wv[r,:]·s[z,:]
        for (int k = lane; k < 768; k += 64)
          a += Wv[(long)r * 768 + k] * sv[z * 768 + k];
      } else {                            // g[z,r] = G[z][r,:]·c1
        const unsigned short* Gz = G + (long)z * 768 * 768;
        for (int k = lane; k < 768; k += 64)
          a += bf2f(Gz[(long)r * 768 + k]) * c1v[k];
      }
      a = wave_red(a);
      if (lane == 0) {
        if (type == 0) a1v[z * 768 + r] = a;
        else if (type == 1) wvv[z * 768 + r] = a;
        else gv[z * 768 + r] = a;
      }
    }
  }
}

// ---- launch 4: Pt GEMM 64^2 (0..1151) + r blocks (1152..1343) --------------
__global__ __launch_bounds__(256, 4) void pt_k(
    const unsigned short* wvb, const unsigned short* H, unsigned short* Pt,
    const float* bv, const float* a1v, const float* wvv, const float* a2v,
    const float* Wv, const float* gv, const float* c1v, const float* sv,
    const float* bq, const float* bk, float* rv)
{
  __shared__ unsigned short lds[2 * 2 * 64 * 64];
  unsigned short* As = lds;
  unsigned short* Bs = lds + 8192;
  const float inv_sqrt_d = 0.036084391824351615f;
  const int bid = blockIdx.x, tid = threadIdx.x;
  if (bid < 1152) {
    const int z = bid & 7, t = bid >> 3;
    gemm64_core<3, 1, 0>(z, (long)(t / 12) * 64, (long)(t % 12) * 64, As, Bs,
        wvb, H, bv, a1v, wvv, a2v, Pt,
        768, 768, 768, 768, 0, 768L * 768, 768L * 768, 0, inv_sqrt_d);
  } else {
    float* red1 = (float*)lds;            // reuse GEMM LDS (disjoint role)
    float* red2 = red1 + 256;
    const int u = bid - 1152;             // 0..191
    const int z = u / 24, r0 = (u % 24) * 32;
    const int wid = tid >> 6, lane = tid & 63;
    float p1 = 0.f, p2 = 0.f;
    for (int d = tid; d < 768; d += 256) {
      p1 += c1v[d] * sv[z * 768 + d];
      p2 += bq[d] * bk[d];
    }
    red1[tid] = p1; red2[tid] = p2;
    __syncthreads();
    for (int st = 128; st > 0; st >>= 1) {
      if (tid < st) { red1[tid] += red1[tid + st]; red2[tid] += red2[tid + st]; }
      __syncthreads();
    }
    const float cs = red1[0], bb = red2[0];
#pragma unroll
    for (int mi = 0; mi < 8; ++mi) {
      const int o = r0 + wid * 8 + mi;
      float a = 0.f;
      for (int k = lane; k < 768; k += 64)
        a += Wv[(long)o * 768 + k] * gv[z * 768 + k];
      a = wave_red(a);
      if (lane == 0)
        rv[z * 768 + o] = inv_sqrt_d *
            (a + cs * bv[o] + bb * (wvv[z * 768 + o] + 2048.0f * bv[o]));
    }
  }
}

// ---- launch 5: out = xb·Pt^T + r   (64^2 tiles, 3072 blocks) ---------------
__global__ __launch_bounds__(256, 4) void final_k(
    const unsigned short* xb, const unsigned short* Pt, const float* rv, float* out)
{
  __shared__ unsigned short lds[2 * 2 * 64 * 64];
  unsigned short* As = lds;
  unsigned short* Bs = lds + 8192;
  const int z = blockIdx.x & 7, t = blockIdx.x >> 3;  // t 0..383
  gemm64_core<1, 0, 0>(z, (long)(t / 12) * 64, (long)(t % 12) * 64, As, Bs,
      xb, Pt, rv, nullptr, nullptr, nullptr, out,
      768, 768, 768, 768, 2048L * 768, 768L * 768, 2048L * 768, 768, 1.0f);
}

extern "C" void kernel_launch(void* const* d_in, const int* in_sizes, int n_in,
                              void* d_out, int out_size, void* d_ws, size_t ws_size,
                              hipStream_t stream) {
  const float* x  = (const float*)d_in[0];
  const float* Wq = (const float*)d_in[1];
  const float* bq = (const float*)d_in[2];
  const float* Wk = (const float*)d_in[3];
  const float* bk = (const float*)d_in[4];
  const float* Wv = (const float*)d_in[5];
  const float* bv = (const float*)d_in[6];
  float* out = (float*)d_out;

  const int Bsz = 8, L = 2048, D = 768;
  const long xN = (long)Bsz * L * D;
  const long wN = (long)D * D;
  const long D2 = wN;

  char* ws = (char*)d_ws;
  unsigned short* xt   = (unsigned short*)ws; ws += xN * 2;
  unsigned short* xb   = (unsigned short*)ws; ws += xN * 2;
  unsigned short* wqtb = (unsigned short*)ws; ws += wN * 2;
  unsigned short* wktb = (unsigned short*)ws; ws += wN * 2;
  unsigned short* wvb  = (unsigned short*)ws; ws += wN * 2;
  unsigned short* Fb   = (unsigned short*)ws; ws += wN * 2;
  unsigned short* regA = (unsigned short*)ws; ws += (long)Bsz * D2 * 2;  // G, later Pt
  unsigned short* regB = (unsigned short*)ws; ws += (long)Bsz * D2 * 2;  // H
  float* partials = (float*)ws; ws += (long)Bsz * D * 32 * 4;
  float* sv  = (float*)ws; ws += (long)Bsz * D * 4;
  float* c1v = (float*)ws; ws += (long)D * 4;
  float* a2v = (float*)ws; ws += (long)D * 4;
  float* a1v = (float*)ws; ws += (long)Bsz * D * 4;
  float* wvv = (float*)ws; ws += (long)Bsz * D * 4;
  float* gv  = (float*)ws; ws += (long)Bsz * D * 4;
  float* rv  = (float*)ws; ws += (long)Bsz * D * 4;

  dim3 blk(256);

  preamble<<<dim3(7584), blk, 0, stream>>>(x, Wq, Wk, Wv, xb, xt, wqtb, wktb, wvb, partials);

  gf_k<<<dim3(800), blk, 0, stream>>>(xt, regA, wqtb, wktb, Fb,
                                      bq, bk, partials, c1v, a2v, sv);

  hv_k<<<dim3(1728), blk, 0, stream>>>(Fb, regA, regB, Wv, sv, c1v, a1v, wvv, gv);

  pt_k<<<dim3(1344), blk, 0, stream>>>(wvb, regB, regA, bv, a1v, wvv, a2v,
                                       Wv, gv, c1v, sv, bq, bk, rv);

  final_k<<<dim3(3072), blk, 0, stream>>>(xb, regA, rv, out);

  (void)in_sizes; (void)n_in; (void)out_size; (void)ws_size;
}

// Round 9
// 173.814 us; speedup vs baseline: 1.0546x; 1.0546x over previous
//
#include <hip/hip_runtime.h>
#include <hip/hip_bf16.h>
#include <stdint.h>

// out = (QK^T/sqrt(d))V = Q (K^T V)/sqrt(d)   (no softmax in ref)
// F = Wq^T Wk;  G = x^T x (symmetric);  H = F G;
// Pt = [Wv H^T + bv a1^T + w a2^T + L bv a2^T]/sqrt(d)
// r[z,o] = [Wv·g + cs bv + bb (w + L bv)]/sqrt(d);  out = xb Pt^T + 1 r^T
// Round-9: 256^2 8-phase counted-vmcnt core (T3+T4) for H, Pt, final.
// G stays 64^2-sym (converted next round if core proves out).

typedef __attribute__((ext_vector_type(8))) short short8;
typedef __attribute__((ext_vector_type(8))) unsigned short ushort8;
typedef __attribute__((ext_vector_type(4))) float f32x4;
typedef __attribute__((address_space(3))) void lds_void;
typedef const __attribute__((address_space(1))) void gmem_void;

#define WAITV(n) asm volatile("s_waitcnt vmcnt(" #n ")" ::: "memory")

__device__ __forceinline__ unsigned short f2bf(float f) {
  union { float f; unsigned u; } v; v.f = f;
  unsigned r = v.u + 0x7fff + ((v.u >> 16) & 1);   // RNE
  return (unsigned short)(r >> 16);
}
__device__ __forceinline__ float bf2f(unsigned short u) {
  union { unsigned u; float f; } v; v.u = ((unsigned)u) << 16; return v.f;
}
__device__ __forceinline__ float wave_red(float a) {
#pragma unroll
  for (int off = 32; off; off >>= 1) a += __shfl_down(a, off);
  return a;
}

// ---------------- preamble: x->xt,xb,col-partials; Wq^T,Wk^T,Wv casts -------
__global__ __launch_bounds__(256) void preamble(
    const float* __restrict__ x, const float* __restrict__ Wq,
    const float* __restrict__ Wk, const float* __restrict__ Wv,
    unsigned short* __restrict__ xb, unsigned short* __restrict__ xt,
    unsigned short* __restrict__ wqtb, unsigned short* __restrict__ wktb,
    unsigned short* __restrict__ wvb, float* __restrict__ partials)
{
  const int bid = blockIdx.x;
  const int tid = threadIdx.x;
  if (bid < 6144) {                       // x role: 64l x 32d tile
    __shared__ float tile[64][33];
    __shared__ float pt[8][32];
    const int z = bid / 768, rem = bid % 768;
    const int l0 = (rem / 24) * 64, d0 = (rem % 24) * 32;
    const int tx = tid & 31, ty = tid >> 5;
    const float* xz = x + ((long)z * 2048 + l0) * 768 + d0;
    unsigned short* xbz = xb + ((long)z * 2048 + l0) * 768 + d0;
    float colacc = 0.f;
#pragma unroll
    for (int i = 0; i < 8; ++i) {
      float v = xz[(long)(i * 8 + ty) * 768 + tx];
      tile[i * 8 + ty][tx] = v;
      xbz[(long)(i * 8 + ty) * 768 + tx] = f2bf(v);
      colacc += v;
    }
    pt[ty][tx] = colacc;
    __syncthreads();
    unsigned short* xtz = xt + ((long)z * 768 + d0) * 2048 + l0;
#pragma unroll
    for (int i = 0; i < 4; ++i) {
      int d = i * 8 + ty;
      ushort2 o; o.x = f2bf(tile[2 * tx][d]); o.y = f2bf(tile[2 * tx + 1][d]);
      *(ushort2*)(xtz + (long)d * 2048 + 2 * tx) = o;
    }
    if (ty == 0) {
      float s = 0.f;
#pragma unroll
      for (int t = 0; t < 8; ++t) s += pt[t][tx];
      partials[((long)z * 768 + d0 + tx) * 32 + (l0 >> 6)] = s;
    }
  } else if (bid < 7296) {                // weight transpose (wq, wk)
    __shared__ float tl[32][33];
    int t = bid - 6144;
    const float* W = (t < 576) ? Wq : Wk;
    unsigned short* O = (t < 576) ? wqtb : wktb;
    t = (t >= 576) ? t - 576 : t;
    const int r0 = (t / 24) * 32, c0 = (t % 24) * 32;
    const int tx = tid & 31, ty = tid >> 5;
    for (int i = ty; i < 32; i += 8) tl[i][tx] = W[(long)(r0 + i) * 768 + c0 + tx];
    __syncthreads();
    for (int i = ty; i < 32; i += 8) O[(long)(c0 + i) * 768 + r0 + tx] = f2bf(tl[tx][i]);
  } else {                                // wv cast, 288 blocks x 2048 elems
    const int t = bid - 7296;
    const long i = ((long)t * 256 + tid) * 8;
    float4 v0 = *(const float4*)(Wv + i);
    float4 v1 = *(const float4*)(Wv + i + 4);
    unsigned short o[8];
    o[0] = f2bf(v0.x); o[1] = f2bf(v0.y); o[2] = f2bf(v0.z); o[3] = f2bf(v0.w);
    o[4] = f2bf(v1.x); o[5] = f2bf(v1.y); o[6] = f2bf(v1.z); o[7] = f2bf(v1.w);
    *(ushort8*)(wvb + i) = *(ushort8*)o;
  }
}

// ------- 64x64-tile GEMM core (kept for G): BK=64, 2-phase dbuf, swizzle ----
template<int BIAS_MODE, int OUT_BF16, int SYM>
__device__ __forceinline__ void gemm64_core(
    int z, long bm, long bn,
    unsigned short* __restrict__ As, unsigned short* __restrict__ Bs,
    const unsigned short* __restrict__ A, const unsigned short* __restrict__ B,
    const float* __restrict__ bias, const float* __restrict__ b2,
    const float* __restrict__ b3, const float* __restrict__ b4,
    void* __restrict__ Cv,
    int K, int lda, int ldb, int ldc,
    long a_bs, long b_bs, long c_bs, long bias_bs, float scale)
{
  const int tid  = threadIdx.x;
  const int wid  = tid >> 6;
  const int lane = tid & 63;
  const unsigned short* Ab = A + (long)z * a_bs;
  const unsigned short* Bb = B + (long)z * b_bs;

  f32x4 acc[2][2];
#pragma unroll
  for (int r = 0; r < 2; ++r)
#pragma unroll
    for (int c = 0; c < 2; ++c) acc[r][c] = (f32x4){0.f, 0.f, 0.f, 0.f};

  const int srow = lane >> 3;
  const int scol = ((lane & 7) ^ srow) * 8;
  const int fr   = lane & 15;
  const int xr   = lane & 7;
  const int kq   = lane >> 4;

#define STAGE64(p, k0) do { \
  _Pragma("unroll") \
  for (int j_ = 0; j_ < 2; ++j_) { \
    const int r_ = wid * 16 + j_ * 8; \
    const unsigned short* ga_ = Ab + (bm + r_ + srow) * (long)lda + (k0) + scol; \
    __builtin_amdgcn_global_load_lds((gmem_void*)ga_, (lds_void*)(As + (p) * 4096 + r_ * 64), 16, 0, 0); \
    const unsigned short* gb_ = Bb + (bn + r_ + srow) * (long)ldb + (k0) + scol; \
    __builtin_amdgcn_global_load_lds((gmem_void*)gb_, (lds_void*)(Bs + (p) * 4096 + r_ * 64), 16, 0, 0); \
  } } while (0)

  const int nt = K / 64;
  STAGE64(0, 0);
  __syncthreads();

  for (int t = 0; t < nt; ++t) {
    const int p = t & 1;
    if (t + 1 < nt) STAGE64(p ^ 1, (t + 1) * 64);
    __builtin_amdgcn_s_setprio(1);
#pragma unroll
    for (int kk = 0; kk < 2; ++kk) {
      short8 af[2], bfr[2];
#pragma unroll
      for (int r = 0; r < 2; ++r) {
        const int row = (wid >> 1) * 32 + r * 16 + fr;
        af[r] = *(const short8*)(As + p * 4096 + row * 64 + (((kk * 4 + kq) ^ xr) << 3));
      }
#pragma unroll
      for (int c = 0; c < 2; ++c) {
        const int row = (wid & 1) * 32 + c * 16 + fr;
        bfr[c] = *(const short8*)(Bs + p * 4096 + row * 64 + (((kk * 4 + kq) ^ xr) << 3));
      }
#pragma unroll
      for (int r = 0; r < 2; ++r)
#pragma unroll
        for (int c = 0; c < 2; ++c)
          acc[r][c] = __builtin_amdgcn_mfma_f32_16x16x32_bf16(af[r], bfr[c], acc[r][c], 0, 0, 0);
    }
    __builtin_amdgcn_s_setprio(0);
    if (t + 1 < nt) __syncthreads();
  }
#undef STAGE64

  const int wr  = (wid >> 1) * 32;
  const int wc  = (wid & 1) * 32;
  const int cr0 = (lane >> 4) * 4;
  const int cc  = lane & 15;
#pragma unroll
  for (int r = 0; r < 2; ++r)
#pragma unroll
    for (int c = 0; c < 2; ++c)
#pragma unroll
      for (int j = 0; j < 4; ++j) {
        long row = bm + wr + r * 16 + cr0 + j;
        long col = bn + wc + c * 16 + cc;
        float v = acc[r][c][j] * scale;
        if (BIAS_MODE == 1) v += bias[z * bias_bs + col];
        long off = (long)z * c_bs + row * (long)ldc + col;
        if (OUT_BF16) {
          ((unsigned short*)Cv)[off] = f2bf(v);
          if (SYM && bm != bn)
            ((unsigned short*)Cv)[(long)z * c_bs + col * (long)ldc + row] = f2bf(v);
        } else {
          ((float*)Cv)[off] = v;
        }
      }
}

// -------- 256^2 8-phase counted-vmcnt core (T3+T4).  512 thr, 8 waves ------
// LDS layout (elements): buf p in [p*32768, p*32768+32768): A [0,16384), B [16384,32768).
// Row-major 64-el rows, T2 swizzle: chunk c of row r stored at (c ^ (r&7)).
// Stage sets (freed-by-phase rotation):  A-set0 = mh0 rows {0-63,128-191},
// A-set1 = {64-127,192-255}; B-set0 = nh0 rows {0-31,64-95,128-159,192-223}.
template<int BIAS_MODE, int OUT_BF16>
__device__ __forceinline__ void gemm256_core(
    int z, long bm, long bn, unsigned short* __restrict__ lds,
    const unsigned short* __restrict__ A, const unsigned short* __restrict__ B,
    const float* __restrict__ bias, const float* __restrict__ b2,
    const float* __restrict__ b3, const float* __restrict__ b4,
    void* __restrict__ Cv,
    int K, int lda, int ldb, int ldc,
    long a_bs, long b_bs, long c_bs, long bias_bs, float scale)
{
  const int tid  = threadIdx.x;
  const int w    = tid >> 6;            // 0..7
  const int lane = tid & 63;
  const int wm   = w >> 2, wn = w & 3;  // 2M x 4N wave grid
  const int fr   = lane & 15, kq = lane >> 4;
  const int srow = lane >> 3;
  const int schunk = (((lane & 7) ^ srow)) << 3;   // pre-swizzled src chunk

  const unsigned short* Ab = A + (long)z * a_bs;
  const unsigned short* Bb = B + (long)z * b_bs;

  f32x4 acc[8][4];
#pragma unroll
  for (int r = 0; r < 8; ++r)
#pragma unroll
    for (int c = 0; c < 4; ++c) acc[r][c] = (f32x4){0.f, 0.f, 0.f, 0.f};

#define STG_A(p_, s_, k_) do { \
  _Pragma("unroll") for (int j_ = 0; j_ < 2; ++j_) { \
    const int idx_ = (w << 1) + j_; \
    const int grp_ = (idx_ < 8 ? idx_ : idx_ + 8) + (s_) * 8; \
    const unsigned short* g_ = Ab + (bm + grp_ * 8 + srow) * (long)lda + (k_) * 64 + schunk; \
    __builtin_amdgcn_global_load_lds((gmem_void*)g_, (lds_void*)(lds + (p_) * 32768 + grp_ * 512), 16, 0, 0); \
  } } while (0)
#define STG_B(p_, s_, k_) do { \
  _Pragma("unroll") for (int j_ = 0; j_ < 2; ++j_) { \
    const int idx_ = (w << 1) + j_; \
    const int grp_ = ((idx_ >> 2) << 3) + (idx_ & 3) + (s_) * 4; \
    const unsigned short* g_ = Bb + (bn + grp_ * 8 + srow) * (long)ldb + (k_) * 64 + schunk; \
    __builtin_amdgcn_global_load_lds((gmem_void*)g_, (lds_void*)(lds + (p_) * 32768 + 16384 + grp_ * 512), 16, 0, 0); \
  } } while (0)

  const int nk = K / 64;
  // prologue: stage K-steps 0 and 1 fully (16 loads)
  STG_A(0, 0, 0); STG_A(0, 1, 0); STG_B(0, 0, 0); STG_B(0, 1, 0);
  STG_A(1, 0, 1); STG_A(1, 1, 1); STG_B(1, 0, 1); STG_B(1, 1, 1);
  WAITV(8);                       // K-step 0's 8 loads landed
  __builtin_amdgcn_s_barrier();

  for (int k = 0; k < nk; ++k) {
    const int p = k & 1;
#pragma unroll
    for (int q = 0; q < 4; ++q) {
      const int mh = q >> 1, nh = q & 1;
      short8 af[4][2], bfv[2][2];
#pragma unroll
      for (int r = 0; r < 4; ++r)
#pragma unroll
        for (int ks = 0; ks < 2; ++ks) {
          const int arow = wm * 128 + mh * 64 + r * 16 + fr;
          af[r][ks] = *(const short8*)(lds + p * 32768 + arow * 64 +
                                       ((((ks << 2) + kq) ^ (arow & 7)) << 3));
        }
#pragma unroll
      for (int c = 0; c < 2; ++c)
#pragma unroll
        for (int ks = 0; ks < 2; ++ks) {
          const int brow = wn * 64 + nh * 32 + c * 16 + fr;
          bfv[c][ks] = *(const short8*)(lds + p * 32768 + 16384 + brow * 64 +
                                        ((((ks << 2) + kq) ^ (brow & 7)) << 3));
        }
      // stage rotation: each set staged once, >=4 phases before first read
      if (q == 0)      { if (k >= 1 && k + 1 < nk) STG_A((k + 1) & 1, 1, k + 1); }
      else if (q == 1) { if (k >= 1 && k + 1 < nk) STG_B((k + 1) & 1, 1, k + 1); }
      else if (q == 2) { if (k + 2 < nk) STG_A(p, 0, k + 2); }
      else             { if (k + 2 < nk) STG_B(p, 0, k + 2); }

      __builtin_amdgcn_s_barrier();
      __builtin_amdgcn_s_setprio(1);
#pragma unroll
      for (int ks = 0; ks < 2; ++ks)
#pragma unroll
        for (int r = 0; r < 4; ++r)
#pragma unroll
          for (int c = 0; c < 2; ++c)
            acc[mh * 4 + r][nh * 2 + c] = __builtin_amdgcn_mfma_f32_16x16x32_bf16(
                af[r][ks], bfv[c][ks], acc[mh * 4 + r][nh * 2 + c], 0, 0, 0);
      __builtin_amdgcn_s_setprio(0);
      if (q == 3 && k + 1 < nk) {          // boundary: next K-step must be resident
        if (k + 2 < nk) WAITV(4);          // 2 newest half-sets may stay in flight
        else            WAITV(0);
      }
      __builtin_amdgcn_s_barrier();
    }
  }
#undef STG_A
#undef STG_B

  const int cr0 = (lane >> 4) * 4, cc = lane & 15;
#pragma unroll
  for (int mr = 0; mr < 8; ++mr)
#pragma unroll
    for (int nc = 0; nc < 4; ++nc)
#pragma unroll
      for (int j = 0; j < 4; ++j) {
        long row = bm + wm * 128 + mr * 16 + cr0 + j;
        long col = bn + wn * 64 + nc * 16 + cc;
        float v = acc[mr][nc][j] * scale;
        if (BIAS_MODE == 1) v += bias[z * bias_bs + col];
        else if (BIAS_MODE == 3)
          v += scale * (bias[row] * (b2[z * 768 + col] + 2048.0f * b4[col])
                        + b3[z * 768 + row] * b4[col]);
        long off = (long)z * c_bs + row * (long)ldc + col;
        if (OUT_BF16) ((unsigned short*)Cv)[off] = f2bf(v);
        else          ((float*)Cv)[off] = v;
      }
}

// ---- launch 2 (unchanged): G upper-tri 64^2 + F + c1,a2 + s ----------------
__global__ __launch_bounds__(256, 4) void gf_k(
    const unsigned short* xt, unsigned short* G,
    const unsigned short* wqtb, const unsigned short* wktb, unsigned short* F,
    const float* bq, const float* bk, const float* partials,
    float* c1v, float* a2v, float* sv)
{
  __shared__ unsigned short lds[2 * 2 * 64 * 64];   // 32 KiB
  unsigned short* As = lds;
  unsigned short* Bs = lds + 8192;
  const int bid = blockIdx.x, tid = threadIdx.x;
  if (bid < 624) {
    const int z = bid & 7;
    int t = bid >> 3;
    int by = 0, off = 0, ww = 12;
    while (t >= off + ww) { off += ww; --ww; ++by; }
    const int bx = by + (t - off);
    gemm64_core<0, 1, 1>(z, (long)by * 64, (long)bx * 64, As, Bs,
        xt, xt, nullptr, nullptr, nullptr, nullptr, G,
        2048, 2048, 2048, 768, 768L * 2048, 768L * 2048, 768L * 768, 0, 1.0f);
  } else if (bid < 768) {
    const int t = bid - 624;
    gemm64_core<0, 1, 0>(0, (long)(t / 12) * 64, (long)(t % 12) * 64, As, Bs,
        wqtb, wktb, nullptr, nullptr, nullptr, nullptr, F,
        768, 768, 768, 768, 0, 0, 0, 0, 1.0f);
  } else if (bid < 792) {
    const int wid = tid >> 6, lane = tid & 63;
    const int r0 = (bid - 768) * 32;
#pragma unroll
    for (int mi = 0; mi < 8; ++mi) {
      const int r = r0 + wid * 8 + mi;
      float ac = 0.f, aa = 0.f;
      for (int k = lane; k < 768; k += 64) {
        ac += bf2f(wktb[(long)r * 768 + k]) * bq[k];
        aa += bf2f(wqtb[(long)r * 768 + k]) * bk[k];
      }
      ac = wave_red(ac); aa = wave_red(aa);
      if (lane == 0) { c1v[r] = ac; a2v[r] = aa; }
    }
  } else {
    const int z = bid - 792;
    for (int d = tid; d < 768; d += 256) {
      const float* pp = partials + ((long)z * 768 + d) * 32;
      float s = 0.f;
#pragma unroll
      for (int j = 0; j < 32; ++j) s += pp[j];
      sv[z * 768 + d] = s;
    }
  }
}

// ---- launch 3: H = F·G 256^2 8-phase (0..71) + a1/w/g GEMVs (72..647) ------
__global__ __launch_bounds__(512, 1) void hv_k(
    const unsigned short* Fb, const unsigned short* G, unsigned short* H,
    const float* Wv, const float* sv, const float* c1v,
    float* a1v, float* wvv, float* gv)
{
  __shared__ unsigned short lds[65536];   // 128 KiB
  const int bid = blockIdx.x, tid = threadIdx.x;
  if (bid < 72) {
    const int z = bid & 7, t = bid >> 3;   // t 0..8
    gemm256_core<0, 1>(z, (long)(t / 3) * 256, (long)(t % 3) * 256, lds,
        Fb, G, nullptr, nullptr, nullptr, nullptr, H,
        768, 768, 768, 768, 0, 768L * 768, 768L * 768, 0, 1.0f);
  } else {
    const int t = bid - 72;               // 0..575
    const int type = t / 192, u = t % 192;
    const int z = u / 24, r0 = (u % 24) * 32;
    const int wid = tid >> 6, lane = tid & 63;
#pragma unroll
    for (int mi = 0; mi < 4; ++mi) {
      const int r = r0 + wid * 4 + mi;
      float a = 0.f;
      if (type == 0) {                    // a1[z,r] = F[r,:]·s[z,:]
        for (int k = lane; k < 768; k += 64)
          a += bf2f(Fb[(long)r * 768 + k]) * sv[z * 768 + k];
      } else if (type == 1) {             // w[z,r] = Wv[r,:]·s[z,:]
        for (int k = lane; k < 768; k += 64)
          a += Wv[(long)r * 768 + k] * sv[z * 768 + k];
      } else {                            // g[z,r] = G[z][r,:]·c1
        const unsigned short* Gz = G + (long)z * 768 * 768;
        for (int k = lane; k < 768; k += 64)
          a += bf2f(Gz[(long)r * 768 + k]) * c1v[k];
      }
      a = wave_red(a);
      if (lane == 0) {
        if (type == 0) a1v[z * 768 + r] = a;
        else if (type == 1) wvv[z * 768 + r] = a;
        else gv[z * 768 + r] = a;
      }
    }
  }
}

// ---- launch 4: Pt 256^2 8-phase (0..71) + r blocks (72..263) ---------------
__global__ __launch_bounds__(512, 1) void pt_k(
    const unsigned short* wvb, const unsigned short* H, unsigned short* Pt,
    const float* bv, const float* a1v, const float* wvv, const float* a2v,
    const float* Wv, const float* gv, const float* c1v, const float* sv,
    const float* bq, const float* bk, float* rv)
{
  __shared__ unsigned short lds[65536];
  const float inv_sqrt_d = 0.036084391824351615f;
  const int bid = blockIdx.x, tid = threadIdx.x;
  if (bid < 72) {
    const int z = bid & 7, t = bid >> 3;
    gemm256_core<3, 1>(z, (long)(t / 3) * 256, (long)(t % 3) * 256, lds,
        wvb, H, bv, a1v, wvv, a2v, Pt,
        768, 768, 768, 768, 0, 768L * 768, 768L * 768, 0, inv_sqrt_d);
  } else {
    float* red1 = (float*)lds;
    float* red2 = red1 + 512;
    const int u = bid - 72;               // 0..191
    const int z = u / 24, r0 = (u % 24) * 32;
    const int wid = tid >> 6, lane = tid & 63;
    float p1 = 0.f, p2 = 0.f;
    for (int d = tid; d < 768; d += 512) {
      p1 += c1v[d] * sv[z * 768 + d];
      p2 += bq[d] * bk[d];
    }
    red1[tid] = p1; red2[tid] = p2;
    __syncthreads();
    for (int st = 256; st > 0; st >>= 1) {
      if (tid < st) { red1[tid] += red1[tid + st]; red2[tid] += red2[tid + st]; }
      __syncthreads();
    }
    const float cs = red1[0], bb = red2[0];
#pragma unroll
    for (int mi = 0; mi < 4; ++mi) {
      const int o = r0 + wid * 4 + mi;
      float a = 0.f;
      for (int k = lane; k < 768; k += 64)
        a += Wv[(long)o * 768 + k] * gv[z * 768 + k];
      a = wave_red(a);
      if (lane == 0)
        rv[z * 768 + o] = inv_sqrt_d *
            (a + cs * bv[o] + bb * (wvv[z * 768 + o] + 2048.0f * bv[o]));
    }
  }
}

// ---- launch 5: out = xb·Pt^T + r   (256^2 8-phase, 192 blocks) -------------
__global__ __launch_bounds__(512, 1) void final_k(
    const unsigned short* xb, const unsigned short* Pt, const float* rv, float* out)
{
  __shared__ unsigned short lds[65536];
  const int z = blockIdx.x & 7, t = blockIdx.x >> 3;  // t 0..23
  gemm256_core<1, 0>(z, (long)(t / 3) * 256, (long)(t % 3) * 256, lds,
      xb, Pt, rv, nullptr, nullptr, nullptr, out,
      768, 768, 768, 768, 2048L * 768, 768L * 768, 2048L * 768, 768, 1.0f);
}

extern "C" void kernel_launch(void* const* d_in, const int* in_sizes, int n_in,
                              void* d_out, int out_size, void* d_ws, size_t ws_size,
                              hipStream_t stream) {
  const float* x  = (const float*)d_in[0];
  const float* Wq = (const float*)d_in[1];
  const float* bq = (const float*)d_in[2];
  const float* Wk = (const float*)d_in[3];
  const float* bk = (const float*)d_in[4];
  const float* Wv = (const float*)d_in[5];
  const float* bv = (const float*)d_in[6];
  float* out = (float*)d_out;

  const int Bsz = 8, L = 2048, D = 768;
  const long xN = (long)Bsz * L * D;
  const long wN = (long)D * D;
  const long D2 = wN;

  char* ws = (char*)d_ws;
  unsigned short* xt   = (unsigned short*)ws; ws += xN * 2;
  unsigned short* xb   = (unsigned short*)ws; ws += xN * 2;
  unsigned short* wqtb = (unsigned short*)ws; ws += wN * 2;
  unsigned short* wktb = (unsigned short*)ws; ws += wN * 2;
  unsigned short* wvb  = (unsigned short*)ws; ws += wN * 2;
  unsigned short* Fb   = (unsigned short*)ws; ws += wN * 2;
  unsigned short* regA = (unsigned short*)ws; ws += (long)Bsz * D2 * 2;  // G, later Pt
  unsigned short* regB = (unsigned short*)ws; ws += (long)Bsz * D2 * 2;  // H
  float* partials = (float*)ws; ws += (long)Bsz * D * 32 * 4;
  float* sv  = (float*)ws; ws += (long)Bsz * D * 4;
  float* c1v = (float*)ws; ws += (long)D * 4;
  float* a2v = (float*)ws; ws += (long)D * 4;
  float* a1v = (float*)ws; ws += (long)Bsz * D * 4;
  float* wvv = (float*)ws; ws += (long)Bsz * D * 4;
  float* gv  = (float*)ws; ws += (long)Bsz * D * 4;
  float* rv  = (float*)ws; ws += (long)Bsz * D * 4;

  preamble<<<dim3(7584), dim3(256), 0, stream>>>(x, Wq, Wk, Wv, xb, xt, wqtb, wktb, wvb, partials);

  gf_k<<<dim3(800), dim3(256), 0, stream>>>(xt, regA, wqtb, wktb, Fb,
                                            bq, bk, partials, c1v, a2v, sv);

  hv_k<<<dim3(648), dim3(512), 0, stream>>>(Fb, regA, regB, Wv, sv, c1v, a1v, wvv, gv);

  pt_k<<<dim3(264), dim3(512), 0, stream>>>(wvb, regB, regA, bv, a1v, wvv, a2v,
                                            Wv, gv, c1v, sv, bq, bk, rv);

  final_k<<<dim3(192), dim3(512), 0, stream>>>(xb, regA, rv, out);

  (void)in_sizes; (void)n_in; (void)out_size; (void)ws_size;
}